// Round 13
// baseline (175.233 us; speedup 1.0000x reference)
//
#include <hip/hip_runtime.h>
#include <hip/hip_bf16.h>

typedef unsigned int u32;
typedef unsigned short u16;
typedef float f32x4 __attribute__((ext_vector_type(4)));
typedef short s16x8 __attribute__((ext_vector_type(8)));

#define B_   2
#define S_   2048
#define HID_ 512
#define H_   8
#define HKV_ 2
#define QB_  8
#define VB_  16
#define NQ_  64
#define HVB_ 128
#define LOG2E_ 1.4426950408889634f
#define MFIX2_ 24.525815695089866f   /* 17 * log2(e) */

// single-instruction RNE f32->bf16 (fptrunc) — proven passing r10-r12.
__device__ __forceinline__ u16 bf16u(float f) {
    return __builtin_bit_cast(u16, (__bf16)f);
}
__device__ __forceinline__ f32x4 mfma16(s16x8 a, s16x8 b, f32x4 c) {
    return __builtin_amdgcn_mfma_f32_16x16x32_bf16(a, b, c, 0, 0, 0);
}
// NaN-free by range analysis: e in [0,inf] -> rcp in [0,1] -> result in [-1,1].
__device__ __forceinline__ float fast_tanh(float x) {
    float e = exp2f(x * (2.f * LOG2E_));
    return 1.f - 2.f * __builtin_amdgcn_rcpf(e + 1.f);
}
__device__ __forceinline__ float fast_sigmoid(float x) {
    return __builtin_amdgcn_rcpf(1.f + exp2f(-LOG2E_ * x));
}
// ablation keep-alives (rule #17: prevent DCE without cost)
__device__ __forceinline__ void keep8h(s16x8 v) {
    const u32* p = (const u32*)&v;
    asm volatile("" :: "v"(p[0]), "v"(p[1]), "v"(p[2]), "v"(p[3]));
}
__device__ __forceinline__ void keepf4(f32x4 v) {
    asm volatile("" :: "v"(v[0]), "v"(v[1]), "v"(v[2]), "v"(v[3]));
}

// ------------------------------------------------- K0: weights -> single bf16 planes
__global__ void k0_convert(const float* __restrict__ Wq, const float* __restrict__ Wk,
                           const float* __restrict__ Wv, const float* __restrict__ Wo,
                           u16* __restrict__ Wc, u16* __restrict__ Wob) {
    int idx = blockIdx.x * 256 + threadIdx.x;          // grid 256 -> 65536 threads
    {
        int n = idx >> 9, k = idx & 511;
        float v = (n < NQ_) ? Wq[n * HID_ + k]
                : (n < NQ_ + 16) ? Wk[(n - NQ_) * HID_ + k]
                : (n < 112) ? Wv[(n - NQ_ - 16) * HID_ + k] : 0.f;
        Wc[idx] = bf16u(v);                            // idx == n*512 + k
    }
    Wob[idx] = bf16u(Wo[idx]);                         // 512*128 == 65536
}

// ------------------------------------------------- K1: projections (single bf16, no LDS)
__global__ __launch_bounds__(256) void k1_proj(
    const float* __restrict__ hidden, const u16* __restrict__ Wc,
    u16* __restrict__ qb, u16* __restrict__ kb, u16* __restrict__ vt)
{
    const int tid = threadIdx.x;
    const int r0 = blockIdx.x * 16;
    const int wv = tid >> 6, lane = tid & 63;
    const int li = lane & 15, lo4 = lane >> 4;

    const float* hrow = hidden + (r0 + li) * HID_;

    f32x4 acc[2];
    acc[0] = (f32x4){0.f, 0.f, 0.f, 0.f};
    acc[1] = (f32x4){0.f, 0.f, 0.f, 0.f};

    #pragma unroll
    for (int kc = 0; kc < 16; ++kc) {
        f32x4 x0 = *(const f32x4*)&hrow[32 * kc + 8 * lo4];
        f32x4 x1 = *(const f32x4*)&hrow[32 * kc + 8 * lo4 + 4];
        s16x8 a = { (short)bf16u(x0[0]), (short)bf16u(x0[1]), (short)bf16u(x0[2]), (short)bf16u(x0[3]),
                    (short)bf16u(x1[0]), (short)bf16u(x1[1]), (short)bf16u(x1[2]), (short)bf16u(x1[3]) };
        #pragma unroll
        for (int u = 0; u < 2; ++u) {
            int n = (wv + 4 * u) * 16 + li;
            s16x8 bfr = *(const s16x8*)&Wc[n * HID_ + 32 * kc + 8 * lo4];
            acc[u] = mfma16(a, bfr, acc[u]);
        }
    }

    #pragma unroll
    for (int u = 0; u < 2; ++u) {
        int n = (wv + 4 * u) * 16 + li;
        if (n < 112) {
            #pragma unroll
            for (int reg = 0; reg < 4; ++reg) {
                int gs = r0 + 4 * lo4 + reg;
                int b = gs >> 11, s = gs & 2047;
                float pre = acc[u][reg];
                if (n < NQ_) {
                    int h = n >> 3, bit = n & 7;
                    qb[(((b * H_ + h) * S_) + s) * QB_ + bit] =
                        bf16u(fast_tanh(pre) * (0.0625f * LOG2E_));
                } else if (n < NQ_ + 16) {
                    int nk = n - NQ_;
                    kb[(((b * HKV_ + (nk >> 3)) * S_) + s) * QB_ + (nk & 7)] = bf16u(fast_tanh(pre));
                } else {
                    int nv = n - NQ_ - 16;
                    int hv = nv >> 4, vb = nv & 15;
                    u16 sig = bf16u(fast_sigmoid(pre));
                    if (s > 0)
                        vt[((b * HKV_ + hv) * VB_ + vb) * S_ + (s - 1)] = sig;   // suffix shift
                    if (s == S_ - 1)
                        vt[((b * HKV_ + hv) * VB_ + vb) * S_ + (S_ - 1)] = 0;
                }
            }
        }
    }
}

// ------------------------------------------------- K2: fused windowed attention (r12, unchanged)
__global__ __launch_bounds__(256, 2) void k2_attn(
    const u16* __restrict__ qb, const u16* __restrict__ kb, const u16* __restrict__ vt,
    const float* __restrict__ vemb0, const float* __restrict__ vemb1,
    u16* __restrict__ AO)
{
    __shared__ __align__(16) u16 psa[4][32 * 72];      // per-wave P scratch
    __shared__ float Om[4][2][16][16];                 // [wave][ig][row][li]
    __shared__ float lv[4][2][16];

    const int bid = blockIdx.x;
    const int rb = bid >> 4;
    const int r  = (rb < 32) ? (63 - rb) : (rb - 32);  // heavy-first complementary pairing
    const int I0 = r * 32;
    const int nJ = ((I0 + 30) >> 6) + 1;               // j <= I0+30 needed
    const int bh = bid & 15;
    const int b = bh >> 3, h = bh & 7, hkv = h >> 2;

    const int g = threadIdx.x >> 6;                    // wave = J-group 0..3
    const int lane = threadIdx.x & 63;
    const int li = lane & 15, lo4 = lane >> 4;

    u16* psw = psa[g];
    const u16* kpl = kb + ((b * HKV_ + hkv) * S_) * QB_ + (li + lo4 - 31) * QB_;
    const u16* vtp = vt + ((b * HKV_ + hkv) * VB_) * S_ + li * S_ + 8 * lo4;

    u16* wadr[2][4];
    const u16* radr[2];
    #pragma unroll
    for (int ig = 0; ig < 2; ++ig) {
        #pragma unroll
        for (int reg = 0; reg < 4; ++reg)
            wadr[ig][reg] = psw + (ig * 16 + 4 * lo4 + reg) * 72 + li;
        radr[ig] = psw + (ig * 16 + li) * 72 + 8 * lo4;
    }

    s16x8 qfu[12];
    {
        const int gr0 = I0 + li - 31 + lo4;
        const u16* qp = qb + ((b * H_ + h) * S_) * QB_ + gr0 * QB_;
        #pragma unroll
        for (int m = 0; m < 12; ++m) {
            s16x8 v = {0, 0, 0, 0, 0, 0, 0, 0};
            if (gr0 + 4 * m >= 0) v = *(const s16x8*)(qp + m * 32);
            qfu[m] = v;
        }
    }

    int ibase[2];
    float binv[2][4], bstep[2][4];
    #pragma unroll
    for (int ig = 0; ig < 2; ++ig) {
        ibase[ig] = I0 + 16 * ig + 4 * lo4;
        #pragma unroll
        for (int reg = 0; reg < 4; ++reg) {
            float d = (float)(ibase[ig] + reg + 1);
            float rc = __builtin_amdgcn_rcpf(d);
            rc = rc * (2.f - d * rc);                  // NR: f32-exact for our range
            binv[ig][reg] = rc * LOG2E_;
            bstep[ig][reg] = 16.f * rc * LOG2E_;
        }
    }

    f32x4 O[2];
    O[0] = (f32x4){0.f, 0.f, 0.f, 0.f};
    O[1] = (f32x4){0.f, 0.f, 0.f, 0.f};
    float lsum[2][4] = {{0.f, 0.f, 0.f, 0.f}, {0.f, 0.f, 0.f, 0.f}};

    s16x8 ld[20];
    {
        const u16* kt = kpl + g * 512;
        if (g == 0) {
            #pragma unroll
            for (int m = 0; m < 20; ++m) {
                s16x8 v = {0, 0, 0, 0, 0, 0, 0, 0};
                if (li + lo4 + 4 * m >= 31) v = *(const s16x8*)(kt + 32 * m);
                ld[m] = v;
            }
        } else {
            #pragma unroll
            for (int m = 0; m < 20; ++m)
                ld[m] = *(const s16x8*)(kt + 32 * m);
        }
    }

    for (int jt = g; jt < nJ; jt += 4) {
        const int J0 = jt * 64;

        s16x8 vfr0 = *(const s16x8*)(vtp + J0);
        s16x8 vfr1 = *(const s16x8*)(vtp + J0 + 32);

        f32x4 sacc[2][4];
        #pragma unroll
        for (int ig = 0; ig < 2; ++ig)
            #pragma unroll
            for (int ns = 0; ns < 4; ++ns)
                sacc[ig][ns] = (f32x4){0.f, 0.f, 0.f, 0.f};
        __builtin_amdgcn_s_setprio(1);
        #pragma unroll
        for (int m = 0; m < 20; ++m) {
            s16x8 f = ld[m];
            {
                int kk = m & 3, ns = m >> 2;
                if (ns < 4) {
                    sacc[0][ns] = mfma16(qfu[kk],     f, sacc[0][ns]);
                    sacc[1][ns] = mfma16(qfu[kk + 4], f, sacc[1][ns]);
                }
            }
            {
                int kk = (m & 3) + 4, ns = (m >> 2) - 1;
                if (ns >= 0) {
                    sacc[0][ns] = mfma16(qfu[kk],     f, sacc[0][ns]);
                    sacc[1][ns] = mfma16(qfu[kk + 4], f, sacc[1][ns]);
                }
            }
        }
        __builtin_amdgcn_s_setprio(0);

        if (jt + 4 < nJ) {
            const u16* kt = kpl + (jt + 4) * 512;
            #pragma unroll
            for (int m = 0; m < 20; ++m)
                ld[m] = *(const s16x8*)(kt + 32 * m);
        }

        const float jlif = (float)(J0 + li);
        #pragma unroll
        for (int ig = 0; ig < 2; ++ig) {
            const bool edgev = (J0 + 63) >= (I0 + 16 * ig);   // wave-uniform
            #pragma unroll
            for (int reg = 0; reg < 4; ++reg) {
                const int irow = ibase[ig] + reg;
                float bns = fmaf(jlif, binv[ig][reg], -MFIX2_);
                float p[4];
                #pragma unroll
                for (int ns = 0; ns < 4; ++ns) {
                    float e = exp2f(sacc[ig][ns][reg] + bns);
                    bns += bstep[ig][reg];
                    if (edgev)
                        e = (J0 + 16 * ns + li < irow) ? e : 0.f;
                    p[ns] = e;
                }
                lsum[ig][reg] += (p[0] + p[1]) + (p[2] + p[3]);
                wadr[ig][reg][0]  = bf16u(p[0]);
                wadr[ig][reg][16] = bf16u(p[1]);
                wadr[ig][reg][32] = bf16u(p[2]);
                wadr[ig][reg][48] = bf16u(p[3]);
            }
            s16x8 pa0 = *(const s16x8*)(radr[ig]);
            s16x8 pa1 = *(const s16x8*)(radr[ig] + 32);
            __builtin_amdgcn_s_setprio(1);
            O[ig] = mfma16(pa0, vfr0, O[ig]);
            O[ig] = mfma16(pa1, vfr1, O[ig]);
            __builtin_amdgcn_s_setprio(0);
        }
    }

    #pragma unroll
    for (int ig = 0; ig < 2; ++ig) {
        #pragma unroll
        for (int reg = 0; reg < 4; ++reg) {
            float l = lsum[ig][reg];
            l += __shfl_xor(l, 1);
            l += __shfl_xor(l, 2);
            l += __shfl_xor(l, 4);
            l += __shfl_xor(l, 8);
            Om[g][ig][4 * lo4 + reg][li] = O[ig][reg];
            if (li == 0) lv[g][ig][4 * lo4 + reg] = l;
        }
    }
    __syncthreads();

    if (g == 0) {
        const int hc = h * VB_ + li;
        const float e0 = vemb0[hc], e1 = vemb1[hc];
        #pragma unroll
        for (int ig = 0; ig < 2; ++ig) {
            #pragma unroll
            for (int reg = 0; reg < 4; ++reg) {
                const int row = 4 * lo4 + reg;
                float Oc = (Om[0][ig][row][li] + Om[1][ig][row][li])
                         + (Om[2][ig][row][li] + Om[3][ig][row][li]);
                float lc = (lv[0][ig][row] + lv[1][ig][row])
                         + (lv[2][ig][row] + lv[3][ig][row]);
                float lr = fmaxf(lc, 1e-30f);
                float rinv = __builtin_amdgcn_rcpf(lr);
                rinv = rinv * (2.f - lr * rinv);
                float o = Oc * rinv;
                const int s = I0 + 16 * ig + row;
                AO[(b * S_ + s) * HVB_ + hc] = bf16u(e0 + o * (e1 - e0));
            }
        }
    }
}

// ------------------------------------------------- K2 ablation probes (measurement only)
// Subtractive ladder on k2's skeleton, identical grid/launch_bounds/LDS/addressing.
// V=0: K/V loads + loop only (REPS=4).  V=1: + QK MFMAs (REPS=2).
// V=2: + P-LDS roundtrip + PV, softmax VALU replaced by raw bf16(sacc) (REPS=2).
template<int V>
__global__ __launch_bounds__(256, 2) void k2_probe(
    const u16* __restrict__ qb, const u16* __restrict__ kb, const u16* __restrict__ vt,
    float* __restrict__ part)
{
    __shared__ __align__(16) u16 psa[4][32 * 72];

    const int bid = blockIdx.x;
    const int rb = bid >> 4;
    const int r  = (rb < 32) ? (63 - rb) : (rb - 32);
    const int I0 = r * 32;
    const int nJ = ((I0 + 30) >> 6) + 1;
    const int bh = bid & 15;
    const int b = bh >> 3, h = bh & 7, hkv = h >> 2;

    const int g = threadIdx.x >> 6;
    const int lane = threadIdx.x & 63;
    const int li = lane & 15, lo4 = lane >> 4;

    u16* psw = psa[g];
    const u16* kpl = kb + ((b * HKV_ + hkv) * S_) * QB_ + (li + lo4 - 31) * QB_;
    const u16* vtp = vt + ((b * HKV_ + hkv) * VB_) * S_ + li * S_ + 8 * lo4;

    u16* wadr[2][4];
    const u16* radr[2];
    #pragma unroll
    for (int ig = 0; ig < 2; ++ig) {
        #pragma unroll
        for (int reg = 0; reg < 4; ++reg)
            wadr[ig][reg] = psw + (ig * 16 + 4 * lo4 + reg) * 72 + li;
        radr[ig] = psw + (ig * 16 + li) * 72 + 8 * lo4;
    }

    s16x8 qfu[12];
    {
        const int gr0 = I0 + li - 31 + lo4;
        const u16* qp = qb + ((b * H_ + h) * S_) * QB_ + gr0 * QB_;
        #pragma unroll
        for (int m = 0; m < 12; ++m) {
            s16x8 v = {0, 0, 0, 0, 0, 0, 0, 0};
            if (gr0 + 4 * m >= 0) v = *(const s16x8*)(qp + m * 32);
            qfu[m] = v;
        }
    }

    const int REPS = (V == 0) ? 4 : 2;
    for (int rep = 0; rep < REPS; ++rep) {
        f32x4 O[2];
        O[0] = (f32x4){0.f, 0.f, 0.f, 0.f};
        O[1] = (f32x4){0.f, 0.f, 0.f, 0.f};

        for (int jt = g; jt < nJ; jt += 4) {
            const int J0 = jt * 64;
            s16x8 vfr0 = *(const s16x8*)(vtp + J0);
            s16x8 vfr1 = *(const s16x8*)(vtp + J0 + 32);

            s16x8 ld[20];
            const u16* kt = kpl + jt * 512;
            #pragma unroll
            for (int m = 0; m < 20; ++m)
                ld[m] = *(const s16x8*)(kt + 32 * m);

            if constexpr (V == 0) {
                #pragma unroll
                for (int m = 0; m < 20; ++m) keep8h(ld[m]);
                keep8h(vfr0);
                keep8h(vfr1);
            } else {
                f32x4 sacc[2][4];
                #pragma unroll
                for (int ig = 0; ig < 2; ++ig)
                    #pragma unroll
                    for (int ns = 0; ns < 4; ++ns)
                        sacc[ig][ns] = (f32x4){0.f, 0.f, 0.f, 0.f};
                #pragma unroll
                for (int m = 0; m < 20; ++m) {
                    s16x8 f = ld[m];
                    {
                        int kk = m & 3, ns = m >> 2;
                        if (ns < 4) {
                            sacc[0][ns] = mfma16(qfu[kk],     f, sacc[0][ns]);
                            sacc[1][ns] = mfma16(qfu[kk + 4], f, sacc[1][ns]);
                        }
                    }
                    {
                        int kk = (m & 3) + 4, ns = (m >> 2) - 1;
                        if (ns >= 0) {
                            sacc[0][ns] = mfma16(qfu[kk],     f, sacc[0][ns]);
                            sacc[1][ns] = mfma16(qfu[kk + 4], f, sacc[1][ns]);
                        }
                    }
                }
                if constexpr (V == 1) {
                    #pragma unroll
                    for (int ig = 0; ig < 2; ++ig)
                        #pragma unroll
                        for (int ns = 0; ns < 4; ++ns)
                            keepf4(sacc[ig][ns]);
                    keep8h(vfr0);
                    keep8h(vfr1);
                } else {     // V == 2: P-LDS roundtrip + PV, no softmax VALU
                    #pragma unroll
                    for (int ig = 0; ig < 2; ++ig) {
                        #pragma unroll
                        for (int reg = 0; reg < 4; ++reg) {
                            wadr[ig][reg][0]  = bf16u(sacc[ig][0][reg]);
                            wadr[ig][reg][16] = bf16u(sacc[ig][1][reg]);
                            wadr[ig][reg][32] = bf16u(sacc[ig][2][reg]);
                            wadr[ig][reg][48] = bf16u(sacc[ig][3][reg]);
                        }
                        s16x8 pa0 = *(const s16x8*)(radr[ig]);
                        s16x8 pa1 = *(const s16x8*)(radr[ig] + 32);
                        O[ig] = mfma16(pa0, vfr0, O[ig]);
                        O[ig] = mfma16(pa1, vfr1, O[ig]);
                    }
                }
            }
        }

        if constexpr (V == 2) {
            float s = (O[0][0] + O[0][1]) + (O[0][2] + O[0][3])
                    + (O[1][0] + O[1][1]) + (O[1][2] + O[1][3]);
            part[(bid * 4 + g) * 64 + lane] = s + (float)rep;
        }
    }
}

// ------------------------------------------------- K3: AO(bf16) @ Wo^T(bf16), no LDS
__global__ __launch_bounds__(256) void k3_out(
    const u16* __restrict__ AO, const u16* __restrict__ Wob,
    float* __restrict__ out)
{
    const int tid = threadIdx.x;
    const int r0 = (int)(blockIdx.x >> 2) * 16;
    const int cg = blockIdx.x & 3;
    const int wv = tid >> 6, lane = tid & 63;
    const int li = lane & 15, lo4 = lane >> 4;

    const u16* arow = AO + (r0 + li) * HVB_;

    f32x4 acc[2];
    acc[0] = (f32x4){0.f, 0.f, 0.f, 0.f};
    acc[1] = (f32x4){0.f, 0.f, 0.f, 0.f};

    #pragma unroll
    for (int kc = 0; kc < 4; ++kc) {
        s16x8 a = *(const s16x8*)&arow[32 * kc + 8 * lo4];
        #pragma unroll
        for (int u = 0; u < 2; ++u) {
            int o = cg * 128 + (wv + 4 * u) * 16 + li;
            s16x8 bfr = *(const s16x8*)&Wob[o * HVB_ + 32 * kc + 8 * lo4];
            acc[u] = mfma16(a, bfr, acc[u]);
        }
    }

    #pragma unroll
    for (int u = 0; u < 2; ++u) {
        int o = cg * 128 + (wv + 4 * u) * 16 + li;
        #pragma unroll
        for (int reg = 0; reg < 4; ++reg)
            out[(r0 + 4 * lo4 + reg) * HID_ + o] = acc[u][reg];
    }
}

// ------------------------------------------------- launch
extern "C" void kernel_launch(void* const* d_in, const int* in_sizes, int n_in,
                              void* d_out, int out_size, void* d_ws, size_t ws_size,
                              hipStream_t stream)
{
    (void)in_sizes; (void)n_in; (void)out_size;
    const float* hidden = (const float*)d_in[0];
    const float* Wq = (const float*)d_in[1];
    const float* Wk = (const float*)d_in[2];
    const float* Wv = (const float*)d_in[3];
    const float* Wo = (const float*)d_in[4];
    const float* ve0 = (const float*)d_in[5];
    const float* ve1 = (const float*)d_in[6];
    float* out = (float*)d_out;

    char* base = (char*)d_ws;
    u16* qb  = (u16*)(base);                        // [B,H,S,8]      524288 B (pre-scaled log2e/16)
    u16* kb  = (u16*)(base + 524288);               // [B,HKV,S,8]    131072 B
    u16* vt  = (u16*)(base + 655360);               // [B,HKV,16,S]   262144 B (shifted, transposed)
    u16* AO  = (u16*)(base + 917504);               // [B*S,128] bf16 1048576 B
    u16* Wc  = (u16*)(base + 1966080);              // [128,512] bf16  131072 B (padded)
    u16* Wob = (u16*)(base + 2097152);              // [512,128] bf16  131072 B -> end 2228224
    float* part = (float*)(base + 2228224);         // probe sink, 1 MB
    if (ws_size < 2228224) return;

    hipLaunchKernelGGL(k0_convert, dim3(256), dim3(256), 0, stream,
                       Wq, Wk, Wv, Wo, Wc, Wob);
    hipLaunchKernelGGL(k1_proj, dim3(256), dim3(256), 0, stream,
                       hidden, Wc, qb, kb, vt);
    hipLaunchKernelGGL(k2_attn, dim3(1024), dim3(256), 0, stream,
                       qb, kb, vt, ve0, ve1, AO);
    if (ws_size >= 2228224u + 1048576u) {
        hipLaunchKernelGGL((k2_probe<0>), dim3(1024), dim3(256), 0, stream, qb, kb, vt, part);
        hipLaunchKernelGGL((k2_probe<1>), dim3(1024), dim3(256), 0, stream, qb, kb, vt, part);
        hipLaunchKernelGGL((k2_probe<2>), dim3(1024), dim3(256), 0, stream, qb, kb, vt, part);
    }
    hipLaunchKernelGGL(k3_out, dim3(1024), dim3(256), 0, stream,
                       AO, Wob, out);
}